// Round 5
// baseline (205.558 us; speedup 1.0000x reference)
//
#include <hip/hip_runtime.h>
#include <math.h>

typedef _Float16 f16;
typedef __attribute__((ext_vector_type(4))) _Float16 f16x4;
typedef __attribute__((ext_vector_type(8))) _Float16 f16x8;
typedef __attribute__((ext_vector_type(4))) float f32x4;
typedef __attribute__((ext_vector_type(16))) float f32x16;

#define NB 2
#define NH 16
#define TQ 1024
#define TK 2048
#define DM 1536
#define HD 96
#define RH 48

__device__ __forceinline__ f32x4 mfma16(f16x8 a, f16x8 b, f32x4 c) {
    return __builtin_amdgcn_mfma_f32_16x16x32_f16(a, b, c, 0, 0, 0);
}

#define GLDS16(gptr, lptr) __builtin_amdgcn_global_load_lds( \
    (const __attribute__((address_space(1))) unsigned int*)(gptr), \
    (__attribute__((address_space(3))) unsigned int*)(lptr), 16, 0, 0)

// ---------------- conversions (fused launches) ----------------
__global__ void cvt_w4(const float4* __restrict__ W0, const float4* __restrict__ W1,
                       const float4* __restrict__ W2, const float4* __restrict__ W3,
                       f16x4* __restrict__ o0, f16x4* __restrict__ o1,
                       f16x4* __restrict__ o2, f16x4* __restrict__ o3, int n4) {
    int i = blockIdx.x * 256 + threadIdx.x;
    if (i >= n4) return;
    const float4* in = blockIdx.y == 0 ? W0 : blockIdx.y == 1 ? W1 : blockIdx.y == 2 ? W2 : W3;
    f16x4* out      = blockIdx.y == 0 ? o0 : blockIdx.y == 1 ? o1 : blockIdx.y == 2 ? o2 : o3;
    float4 v = in[i];
    f16x4 o;
    o[0] = (f16)v.x; o[1] = (f16)v.y; o[2] = (f16)v.z; o[3] = (f16)v.w;
    out[i] = o;
}

__global__ void cvt_xm(const float4* __restrict__ X, const float4* __restrict__ M,
                       f16x4* __restrict__ ox, f16x4* __restrict__ om, int nx4, int nm4) {
    int i = blockIdx.x * 256 + threadIdx.x;
    int n = blockIdx.y == 0 ? nx4 : nm4;
    if (i >= n) return;
    const float4* in = blockIdx.y == 0 ? X : M;
    f16x4* out = blockIdx.y == 0 ? ox : om;
    float4 v = in[i];
    f16x4 o;
    o[0] = (f16)v.x; o[1] = (f16)v.y; o[2] = (f16)v.z; o[3] = (f16)v.w;
    out[i] = o;
}

// ---------------- RoPE sin/cos tables: [B*T][48] ----------------
__global__ void rope_tab2(const float* __restrict__ cq, const float* __restrict__ cm,
                          float* __restrict__ sq, float* __restrict__ cqo,
                          float* __restrict__ sk, float* __restrict__ cko,
                          int nq, int nk) {
    int i = blockIdx.x * 256 + threadIdx.x;
    int n = blockIdx.y == 0 ? nq : nk;
    if (i >= n) return;
    const float* coords = blockIdx.y == 0 ? cq : cm;
    float* sinT = blockIdx.y == 0 ? sq : sk;
    float* cosT = blockIdx.y == 0 ? cqo : cko;
    int bt = i / 48, idx = i - bt * 48;
    int axis = idx >> 4, f = idx & 15;
    float inv = powf(10000.f, -(float)f * (1.f / 16.f));
    float ang = coords[bt * 3 + axis] * inv;
    sinT[i] = sinf(ang);
    cosT[i] = cosf(ang);
}

// ---------------- RoPE rotation in-place on [B,H,T,stride] f16 ----------------
__global__ void rope_apply_k(f16* __restrict__ qk, const float* __restrict__ sinT,
                             const float* __restrict__ cosT, int T, int stride,
                             float scale, int n) {
    int i = blockIdx.x * 256 + threadIdx.x;
    if (i >= n) return;
    int p = i % 48;
    int rest = i / 48;              // (b*NH + h)*T + t
    int t = rest % T;
    int b = rest / (NH * T);
    long base = (long)rest * stride;
    float x1 = (float)qk[base + p];
    float x2 = (float)qk[base + p + RH];
    int ti = (b * T + t) * 48 + p;
    float s = sinT[ti], c = cosT[ti];
    qk[base + p]      = (f16)((x1 * c - x2 * s) * scale);
    qk[base + p + RH] = (f16)((x2 * c + x1 * s) * scale);
}

// ---------------- GEMM v3: depth-2 pipeline, BK=32, multi-block/CU ----------------
// C[m,n] = sum_k A[m,k]*W[n,k] + bias[n].  BN=128.
// BM=256: 512 thr (8 waves 4x2), LDS 72KB -> 2 blocks/CU.
// BM=128: 256 thr (4 waves 2x2), LDS 48KB -> 3 blocks/CU.
// 3 LDS buffers; iter t: vmcnt(LPS) -> barrier -> STAGE(t+2) -> frags -> MFMA.
// Swizzle for 64B rows: seg ^= (row^(row>>2))&3  (2 lanes/bank on frag reads).
// MODE 1: f32 row-major. MODE 4: fused K|V (bx<12 -> K padded [B,H,T,128],
// else V^T [B,H,96,TK]). MODE 5: f16 [B,H,T,96].
template <int MODE, int BM>
__global__ __launch_bounds__(BM == 256 ? 512 : 256, BM == 256 ? 4 : 3) void gemm3p(
    const f16* __restrict__ A, const f16* __restrict__ Wa, const f16* __restrict__ Wb,
    const float* __restrict__ ba, const float* __restrict__ bb,
    void* __restrict__ outa, void* __restrict__ outb,
    int M, int N, int K, int T) {
    constexpr int TPB = (BM == 256) ? 512 : 256;
    constexpr int NW_M = (BM == 256) ? 4 : 2;
    constexpr int RA = (BM * 64) / (TPB * 16);     // 2
    constexpr int RB = (128 * 64) / (TPB * 16);    // 1 (BM=256) or 2 (BM=128)
    constexpr int LPS = RA + RB;                   // 3 or 4
    constexpr int ABUF = BM * 32;                  // f16 per A tile
    constexpr int BUFSZ = (BM + 128) * 32;

    __shared__ f16 Buf[3][BUFSZ];

    const int tid = threadIdx.x;
    const int w = tid >> 6, lane = tid & 63;
    const int l15 = lane & 15, g = lane >> 4;
    int bx = blockIdx.x;
    const f16* W = Wa; const float* bias = ba; void* outp = outa;
    bool sel = false;
    if (MODE == 4 && bx >= 12) { sel = true; W = Wb; bias = bb; outp = outb; bx -= 12; }
    const int m0 = blockIdx.y * BM, n0 = bx * 128;
    const int wm = (w % NW_M) * 64;
    const int wn = (w / NW_M) * 64;

    // pre-swizzled per-lane global source offsets (f16 units)
    int asrc[RA], bsrc[RB];
#pragma unroll
    for (int r = 0; r < RA; r++) {
        int L = r * (TPB * 16) + tid * 16;         // linear byte offset in A region
        int row = L >> 6, seg = (L >> 4) & 3;
        asrc[r] = row * K + ((seg ^ ((row ^ (row >> 2)) & 3)) << 3);
    }
#pragma unroll
    for (int r = 0; r < RB; r++) {
        int L = r * (TPB * 16) + tid * 16;
        int row = L >> 6, seg = (L >> 4) & 3;
        bsrc[r] = row * K + ((seg ^ ((row ^ (row >> 2)) & 3)) << 3);
    }
    const f16* Ag = A + (long)m0 * K;
    const f16* Bg = W + (long)n0 * K;

    // fragment LDS element offsets (fixed per thread)
    int aoff[4], boff[4];
#pragma unroll
    for (int i = 0; i < 4; i++) {
        int row = wm + i * 16 + l15;
        aoff[i] = row * 32 + ((g ^ ((row ^ (row >> 2)) & 3)) << 3);
    }
#pragma unroll
    for (int j = 0; j < 4; j++) {
        int row = wn + j * 16 + l15;
        boff[j] = ABUF + row * 32 + ((g ^ ((row ^ (row >> 2)) & 3)) << 3);
    }

#define STAGE3(bufi, kt) do { \
    _Pragma("unroll") for (int r_ = 0; r_ < RA; r_++) \
        GLDS16(Ag + asrc[r_] + (kt) * 32, &Buf[bufi][r_ * (TPB * 8) + w * 512]); \
    _Pragma("unroll") for (int r_ = 0; r_ < RB; r_++) \
        GLDS16(Bg + bsrc[r_] + (kt) * 32, &Buf[bufi][ABUF + r_ * (TPB * 8) + w * 512]); \
} while (0)

    f32x4 acc[4][4] = {};
    const int NT = K >> 5;                 // 48 (divisible by 3)

    STAGE3(0, 0);
    STAGE3(1, 1);

#pragma unroll 1
    for (int t = 0; t < NT; t += 3) {
#pragma unroll
        for (int u = 0; u < 3; u++) {
            asm volatile("s_waitcnt vmcnt(%0)" :: "n"(LPS) : "memory");
            __builtin_amdgcn_s_barrier();
            __builtin_amdgcn_sched_barrier(0);
            if (t + u + 2 < NT) {
                constexpr int NB3[3] = {2, 0, 1};
                STAGE3(NB3[u], t + u + 2);
            }
            __builtin_amdgcn_sched_barrier(0);

            f16x8 af[4], bf[4];
#pragma unroll
            for (int i = 0; i < 4; i++) af[i] = *(const f16x8*)&Buf[u][aoff[i]];
#pragma unroll
            for (int j = 0; j < 4; j++) bf[j] = *(const f16x8*)&Buf[u][boff[j]];
            __builtin_amdgcn_s_setprio(1);
#pragma unroll
            for (int i = 0; i < 4; i++)
#pragma unroll
                for (int j = 0; j < 4; j++)
                    acc[i][j] = mfma16(af[i], bf[j], acc[i][j]);
            __builtin_amdgcn_s_setprio(0);
        }
    }
#undef STAGE3

    // ---- epilogue ----
#pragma unroll
    for (int i = 0; i < 4; i++) {
#pragma unroll
        for (int j = 0; j < 4; j++) {
            const int n = n0 + wn + j * 16 + l15;
            const int mb = m0 + wm + i * 16 + g * 4;
            if (MODE == 4 && sel) {            // V^T [B,H,96,TK]
                int bq = mb / T, t = mb - bq * T;
                int hh = n / HD, hd = n - hh * HD;
                f16x4 pk;
#pragma unroll
                for (int r = 0; r < 4; r++) pk[r] = (f16)(acc[i][j][r] + bias[n]);
                *(f16x4*)&((f16*)outp)[(((long)bq * NH + hh) * HD + hd) * TK + t] = pk;
            } else if (MODE == 4) {            // K padded [B,H,T,128]
#pragma unroll
                for (int r = 0; r < 4; r++) {
                    int m = mb + r;
                    int bq = m / T, t = m - bq * T;
                    int hh = n / HD, hd = n - hh * HD;
                    ((f16*)outp)[(((long)bq * NH + hh) * T + t) * 128 + hd] = (f16)(acc[i][j][r] + bias[n]);
                }
            } else if (MODE == 5) {            // Q [B,H,T,96]
#pragma unroll
                for (int r = 0; r < 4; r++) {
                    int m = mb + r;
                    int bq = m / T, t = m - bq * T;
                    int hh = n / HD, hd = n - hh * HD;
                    ((f16*)outp)[(((long)bq * NH + hh) * T + t) * 96 + hd] = (f16)(acc[i][j][r] + bias[n]);
                }
            } else {                           // f32 row-major
#pragma unroll
                for (int r = 0; r < 4; r++)
                    ((float*)outp)[(long)(mb + r) * N + n] = acc[i][j][r] + bias[n];
            }
        }
    }
}

// ---------------- Flash attention (round-3 structure, unchanged) ----------------
__global__ __launch_bounds__(256, 2) void attn_fwd(
    const f16* __restrict__ Q, const f16* __restrict__ Kg,
    const f16* __restrict__ Vg, f16* __restrict__ O) {
    __shared__ f16 Kl[2][64 * 128];
    __shared__ f16 Vl[2][96 * 64];
    __shared__ f16 Pl[4][32 * 64];

    const int tid = threadIdx.x, w = tid >> 6, lane = tid & 63;
    const int q31 = lane & 31, hf = lane >> 5;
    const int half = w >> 1, u = w & 1;

    const int linear = blockIdx.x + (int)(gridDim.x * (blockIdx.y + gridDim.y * blockIdx.z));
    const int wid = (linear & 7) * 64 + (linear >> 3);
    const int qc = wid & 15, h = (wid >> 4) & 15, b = wid >> 8;

    const long kbase = (long)(b * NH + h) * TK * 128;
    const long vbase = (long)(b * NH + h) * HD * TK;
    const long qbase = (long)(b * NH + h) * TQ * 96;
    const int q0 = qc * 64 + u * 32;

    int ksrc[8], vsrc[6];
#pragma unroll
    for (int i = 0; i < 8; i++) {
        int L = (u * 8 + i) * 1024 + lane * 16;
        int r = L >> 8, s = (L >> 4) & 15;
        ksrc[i] = r * 128 + ((s ^ (r & 7)) << 3);
    }
#pragma unroll
    for (int i = 0; i < 6; i++) {
        int L = (u * 6 + i) * 1024 + lane * 16;
        int r = L >> 7, s = (L >> 4) & 7;
        vsrc[i] = r * TK + ((s ^ (r & 7)) << 3);
    }

    f16x8 qf[6];
#pragma unroll
    for (int s = 0; s < 6; s++)
        qf[s] = *(const f16x8*)&Q[qbase + (long)(q0 + q31) * 96 + hf * 8 + 16 * s];

    float mx = -3e38f, ls = 0.f;
    f32x16 acc[3] = {};

#define STAGE(c_) do { \
    const f16* kp_ = Kg + kbase + (long)(half * 16 + (c_)) * (64 * 128); \
    _Pragma("unroll") for (int i_ = 0; i_ < 8; i_++) \
        GLDS16(kp_ + ksrc[i_], &Kl[half][(u * 8 + i_) * 512]); \
    const f16* vp_ = Vg + vbase + (half * 16 + (c_)) * 64; \
    _Pragma("unroll") for (int i_ = 0; i_ < 6; i_++) \
        GLDS16(vp_ + vsrc[i_], &Vl[half][(u * 6 + i_) * 512]); \
} while (0)

    STAGE(0);

    for (int c = 0; c < 16; ++c) {
        __syncthreads();

        f32x16 st[2] = {};
#pragma unroll
        for (int kt = 0; kt < 2; kt++)
#pragma unroll
            for (int s = 0; s < 6; s++) {
                f16x8 kf = *(const f16x8*)&Kl[half][(kt * 32 + q31) * 128 +
                                                    (((hf + 2 * s) ^ (q31 & 7)) << 3)];
                st[kt] = __builtin_amdgcn_mfma_f32_32x32x16_f16(kf, qf[s], st[kt], 0, 0, 0);
            }

        float t16[16];
#pragma unroll
        for (int r = 0; r < 16; r++) t16[r] = fmaxf(st[0][r], st[1][r]);
#pragma unroll
        for (int o = 8; o >= 1; o >>= 1)
#pragma unroll
            for (int r = 0; r < o; r++) t16[r] = fmaxf(t16[r], t16[r + o]);
        float cm = fmaxf(t16[0], __shfl_xor(t16[0], 32));
        float mn = fmaxf(mx, cm);
        float corr = exp2f(mx - mn);
        mx = mn;
#pragma unroll
        for (int kt = 0; kt < 2; kt++)
#pragma unroll
            for (int r = 0; r < 16; r++) st[kt][r] = exp2f(st[kt][r] - mn);
        float s16[16];
#pragma unroll
        for (int r = 0; r < 16; r++) s16[r] = st[0][r] + st[1][r];
#pragma unroll
        for (int o = 8; o >= 1; o >>= 1)
#pragma unroll
            for (int r = 0; r < o; r++) s16[r] += s16[r + o];
        ls = ls * corr + s16[0];
#pragma unroll
        for (int dt = 0; dt < 3; dt++)
#pragma unroll
            for (int r = 0; r < 16; r++) acc[dt][r] *= corr;

#pragma unroll
        for (int kt = 0; kt < 2; kt++)
#pragma unroll
            for (int jq = 0; jq < 4; jq++) {
                f16x4 pk;
#pragma unroll
                for (int e = 0; e < 4; e++) pk[e] = (f16)st[kt][jq * 4 + e];
                int seg = kt * 4 + jq;
                *(f16x4*)&Pl[w][q31 * 64 + ((seg ^ (q31 & 7)) << 3) + hf * 4] = pk;
            }

#pragma unroll
        for (int ks = 0; ks < 4; ks++) {
            f16x8 pf = *(const f16x8*)&Pl[w][q31 * 64 + (((hf + 2 * ks) ^ (q31 & 7)) << 3)];
#pragma unroll
            for (int dt = 0; dt < 3; dt++) {
                f16x8 vf = *(const f16x8*)&Vl[half][(dt * 32 + q31) * 64 +
                                                    (((hf + 2 * ks) ^ (q31 & 7)) << 3)];
                acc[dt] = __builtin_amdgcn_mfma_f32_32x32x16_f16(vf, pf, acc[dt], 0, 0, 0);
            }
        }

        __syncthreads();
        if (c < 15) STAGE(c + 1);
    }

    ls += __shfl_xor(ls, 32);
    float* dump = (float*)&Kl[0][0] + u * (64 * 52);
    __syncthreads();
    if (half == 1) {
        float* dl = dump + lane * 52;
        dl[0] = mx; dl[1] = ls;
#pragma unroll
        for (int dt = 0; dt < 3; dt++)
#pragma unroll
            for (int r = 0; r < 16; r++) dl[2 + dt * 16 + r] = acc[dt][r];
    }
    __syncthreads();
    if (half == 0) {
        const float* dl = dump + lane * 52;
        float mb = dl[0], lsb = dl[1];
        float mf = fmaxf(mx, mb);
        float ca = exp2f(mx - mf), cb = exp2f(mb - mf);
        float inv = 1.f / (ls * ca + lsb * cb);
        const long orow = (long)(b * TQ + q0 + q31) * DM + h * 96;
#pragma unroll
        for (int dt = 0; dt < 3; dt++)
#pragma unroll
            for (int jq = 0; jq < 4; jq++) {
                f16x4 ov;
#pragma unroll
                for (int e = 0; e < 4; e++) {
                    int r = jq * 4 + e;
                    ov[e] = (f16)((acc[dt][r] * ca + dl[2 + dt * 16 + r] * cb) * inv);
                }
                *(f16x4*)&O[orow + dt * 32 + jq * 8 + hf * 4] = ov;
            }
    }
}

// ---------------- host ----------------
extern "C" void kernel_launch(void* const* d_in, const int* in_sizes, int n_in,
                              void* d_out, int out_size, void* d_ws, size_t ws_size,
                              hipStream_t stream) {
    const float* x   = (const float*)d_in[0];
    const float* mem = (const float*)d_in[1];
    const float* qc  = (const float*)d_in[2];
    const float* mc  = (const float*)d_in[3];
    const float* Wq  = (const float*)d_in[4];
    const float* bq  = (const float*)d_in[5];
    const float* Wk  = (const float*)d_in[6];
    const float* bk  = (const float*)d_in[7];
    const float* Wv  = (const float*)d_in[8];
    const float* bv  = (const float*)d_in[9];
    const float* Wo  = (const float*)d_in[10];
    const float* bo  = (const float*)d_in[11];
    float* out = (float*)d_out;

    const long nx  = (long)NB * TQ * DM;
    const long nm  = (long)NB * TK * DM;
    const long nw  = (long)DM * DM;
    const long nq  = (long)NB * NH * TQ * 96;
    const long nkp = (long)NB * NH * TK * 128;
    const long nvt = (long)NB * NH * HD * TK;

    char* ws = (char*)d_ws;
    size_t off = 0;
    auto alloc = [&](size_t bytes) { size_t o = off; off = (off + bytes + 255) & ~(size_t)255; return o; };
    f16* x16   = (f16*)(ws + alloc(nx * 2));     // reused as at16 after Q-proj
    f16* mem16 = (f16*)(ws + alloc(nm * 2));
    f16* wq16  = (f16*)(ws + alloc(nw * 2));
    f16* wk16  = (f16*)(ws + alloc(nw * 2));
    f16* wv16  = (f16*)(ws + alloc(nw * 2));
    f16* wo16  = (f16*)(ws + alloc(nw * 2));
    f16* q16   = (f16*)(ws + alloc(nq * 2));
    f16* k16p  = (f16*)(ws + alloc(nkp * 2));
    f16* vt16  = (f16*)(ws + alloc(nvt * 2));
    float* sinq = (float*)(ws + alloc((size_t)NB * TQ * 48 * 4));
    float* cosq = (float*)(ws + alloc((size_t)NB * TQ * 48 * 4));
    float* sink = (float*)(ws + alloc((size_t)NB * TK * 48 * 4));
    float* cosk = (float*)(ws + alloc((size_t)NB * TK * 48 * 4));
    f16* at16 = x16;

    cvt_w4<<<dim3((int)(nw / 4 / 256), 4), 256, 0, stream>>>(
        (const float4*)Wq, (const float4*)Wk, (const float4*)Wv, (const float4*)Wo,
        (f16x4*)wq16, (f16x4*)wk16, (f16x4*)wv16, (f16x4*)wo16, (int)(nw / 4));
    cvt_xm<<<dim3((int)(nm / 4 / 256), 2), 256, 0, stream>>>(
        (const float4*)x, (const float4*)mem, (f16x4*)x16, (f16x4*)mem16,
        (int)(nx / 4), (int)(nm / 4));

    rope_tab2<<<dim3((NB * TK * 48 + 255) / 256, 2), 256, 0, stream>>>(
        qc, mc, sinq, cosq, sink, cosk, NB * TQ * 48, NB * TK * 48);

    // projections: Q (128x128, 256 thr, 192 blocks), fused K|V (256x128, 512 thr, 384 blocks)
    gemm3p<5, 128><<<dim3(12, 16), 256, 0, stream>>>(
        x16, wq16, nullptr, bq, nullptr, q16, nullptr, NB * TQ, DM, DM, TQ);
    gemm3p<4, 256><<<dim3(24, 16), 512, 0, stream>>>(
        mem16, wk16, wv16, bk, bv, k16p, vt16, NB * TK, DM, DM, TK);

    const float qscale = 0.10206207261596577f * 1.4426950408889634f;  // 1/sqrt(96)*log2(e)
    rope_apply_k<<<(NB * NH * TQ * 48 + 255) / 256, 256, 0, stream>>>(
        q16, sinq, cosq, TQ, 96, qscale, NB * NH * TQ * 48);
    rope_apply_k<<<(NB * NH * TK * 48 + 255) / 256, 256, 0, stream>>>(
        k16p, sink, cosk, TK, 128, 1.0f, NB * NH * TK * 48);

    attn_fwd<<<dim3(16, 16, 2), 256, 0, stream>>>(q16, k16p, vt16, at16);

    gemm3p<1, 128><<<dim3(12, 16), 256, 0, stream>>>(
        at16, wo16, nullptr, bo, nullptr, out, nullptr, NB * TQ, DM, DM, TQ);
}

// Round 6
// 205.278 us; speedup vs baseline: 1.0014x; 1.0014x over previous
//
#include <hip/hip_runtime.h>
#include <math.h>

typedef _Float16 f16;
typedef __attribute__((ext_vector_type(4))) _Float16 f16x4;
typedef __attribute__((ext_vector_type(8))) _Float16 f16x8;
typedef __attribute__((ext_vector_type(4))) float f32x4;
typedef __attribute__((ext_vector_type(16))) float f32x16;

#define NB 2
#define NH 16
#define TQ 1024
#define TK 2048
#define DM 1536
#define HD 96
#define RH 48

__device__ __forceinline__ f32x4 mfma16(f16x8 a, f16x8 b, f32x4 c) {
    return __builtin_amdgcn_mfma_f32_16x16x32_f16(a, b, c, 0, 0, 0);
}

#define GLDS16(gptr, lptr) __builtin_amdgcn_global_load_lds( \
    (const __attribute__((address_space(1))) unsigned int*)(gptr), \
    (__attribute__((address_space(3))) unsigned int*)(lptr), 16, 0, 0)

// ---------------- conversions (fused launches) ----------------
__global__ void cvt_w4(const float4* __restrict__ W0, const float4* __restrict__ W1,
                       const float4* __restrict__ W2, const float4* __restrict__ W3,
                       f16x4* __restrict__ o0, f16x4* __restrict__ o1,
                       f16x4* __restrict__ o2, f16x4* __restrict__ o3, int n4) {
    int i = blockIdx.x * 256 + threadIdx.x;
    if (i >= n4) return;
    const float4* in = blockIdx.y == 0 ? W0 : blockIdx.y == 1 ? W1 : blockIdx.y == 2 ? W2 : W3;
    f16x4* out      = blockIdx.y == 0 ? o0 : blockIdx.y == 1 ? o1 : blockIdx.y == 2 ? o2 : o3;
    float4 v = in[i];
    f16x4 o;
    o[0] = (f16)v.x; o[1] = (f16)v.y; o[2] = (f16)v.z; o[3] = (f16)v.w;
    out[i] = o;
}

__global__ void cvt_xm(const float4* __restrict__ X, const float4* __restrict__ M,
                       f16x4* __restrict__ ox, f16x4* __restrict__ om, int nx4, int nm4) {
    int i = blockIdx.x * 256 + threadIdx.x;
    int n = blockIdx.y == 0 ? nx4 : nm4;
    if (i >= n) return;
    const float4* in = blockIdx.y == 0 ? X : M;
    f16x4* out = blockIdx.y == 0 ? ox : om;
    float4 v = in[i];
    f16x4 o;
    o[0] = (f16)v.x; o[1] = (f16)v.y; o[2] = (f16)v.z; o[3] = (f16)v.w;
    out[i] = o;
}

// ---------------- RoPE sin/cos tables: [B*T][48] ----------------
__global__ void rope_tab2(const float* __restrict__ cq, const float* __restrict__ cm,
                          float* __restrict__ sq, float* __restrict__ cqo,
                          float* __restrict__ sk, float* __restrict__ cko,
                          int nq, int nk) {
    int i = blockIdx.x * 256 + threadIdx.x;
    int n = blockIdx.y == 0 ? nq : nk;
    if (i >= n) return;
    const float* coords = blockIdx.y == 0 ? cq : cm;
    float* sinT = blockIdx.y == 0 ? sq : sk;
    float* cosT = blockIdx.y == 0 ? cqo : cko;
    int bt = i / 48, idx = i - bt * 48;
    int axis = idx >> 4, f = idx & 15;
    float inv = powf(10000.f, -(float)f * (1.f / 16.f));
    float ang = coords[bt * 3 + axis] * inv;
    sinT[i] = sinf(ang);
    cosT[i] = cosf(ang);
}

// ---------------- RoPE rotation in-place on [B,H,T,stride] f16 ----------------
__global__ void rope_apply_k(f16* __restrict__ qk, const float* __restrict__ sinT,
                             const float* __restrict__ cosT, int T, int stride,
                             float scale, int n) {
    int i = blockIdx.x * 256 + threadIdx.x;
    if (i >= n) return;
    int p = i % 48;
    int rest = i / 48;              // (b*NH + h)*T + t
    int t = rest % T;
    int b = rest / (NH * T);
    long base = (long)rest * stride;
    float x1 = (float)qk[base + p];
    float x2 = (float)qk[base + p + RH];
    int ti = (b * T + t) * 48 + p;
    float s = sinT[ti], c = cosT[ti];
    qk[base + p]      = (f16)((x1 * c - x2 * s) * scale);
    qk[base + p + RH] = (f16)((x2 * c + x1 * s) * scale);
}

// ---------------- GEMM v3: depth-2 pipeline, BK=32, multi-block/CU ----------------
// C[m,n] = sum_k A[m,k]*W[n,k] + bias[n].  BN=128.
// BM=256: 512 thr (8 waves 4x2), LDS 72KB -> 2 blocks/CU.
// BM=128: 256 thr (4 waves 2x2), LDS 48KB -> 3 blocks/CU.
// 3 LDS buffers; iter t: vmcnt(LPS) -> barrier -> STAGE(t+2) -> frags -> MFMA.
// Swizzle for 64B rows: seg ^= (row^(row>>2))&3  (2 lanes/bank on frag reads).
// MODE 1: f32 row-major. MODE 4: fused K|V (bx<12 -> K padded [B,H,T,128],
// else V^T [B,H,96,TK]). MODE 5: f16 [B,H,T,96].
template <int MODE, int BM>
__global__ __launch_bounds__(BM == 256 ? 512 : 256, BM == 256 ? 4 : 3) void gemm3p(
    const f16* __restrict__ A, const f16* __restrict__ Wa, const f16* __restrict__ Wb,
    const float* __restrict__ ba, const float* __restrict__ bb,
    void* __restrict__ outa, void* __restrict__ outb,
    int M, int N, int K, int T) {
    constexpr int TPB = (BM == 256) ? 512 : 256;
    constexpr int NW_M = (BM == 256) ? 4 : 2;
    constexpr int RA = (BM * 64) / (TPB * 16);     // 2
    constexpr int RB = (128 * 64) / (TPB * 16);    // 1 (BM=256) or 2 (BM=128)
    constexpr int LPS = RA + RB;                   // 3 or 4
    constexpr int ABUF = BM * 32;                  // f16 per A tile
    constexpr int BUFSZ = (BM + 128) * 32;

    __shared__ f16 Buf[3][BUFSZ];

    const int tid = threadIdx.x;
    const int w = tid >> 6, lane = tid & 63;
    const int l15 = lane & 15, g = lane >> 4;
    int bx = blockIdx.x;
    const f16* W = Wa; const float* bias = ba; void* outp = outa;
    bool sel = false;
    if (MODE == 4 && bx >= 12) { sel = true; W = Wb; bias = bb; outp = outb; bx -= 12; }
    const int m0 = blockIdx.y * BM, n0 = bx * 128;
    const int wm = (w % NW_M) * 64;
    const int wn = (w / NW_M) * 64;

    // pre-swizzled per-lane global source offsets (f16 units)
    int asrc[RA], bsrc[RB];
#pragma unroll
    for (int r = 0; r < RA; r++) {
        int L = r * (TPB * 16) + tid * 16;         // linear byte offset in A region
        int row = L >> 6, seg = (L >> 4) & 3;
        asrc[r] = row * K + ((seg ^ ((row ^ (row >> 2)) & 3)) << 3);
    }
#pragma unroll
    for (int r = 0; r < RB; r++) {
        int L = r * (TPB * 16) + tid * 16;
        int row = L >> 6, seg = (L >> 4) & 3;
        bsrc[r] = row * K + ((seg ^ ((row ^ (row >> 2)) & 3)) << 3);
    }
    const f16* Ag = A + (long)m0 * K;
    const f16* Bg = W + (long)n0 * K;

    // fragment LDS element offsets (fixed per thread)
    int aoff[4], boff[4];
#pragma unroll
    for (int i = 0; i < 4; i++) {
        int row = wm + i * 16 + l15;
        aoff[i] = row * 32 + ((g ^ ((row ^ (row >> 2)) & 3)) << 3);
    }
#pragma unroll
    for (int j = 0; j < 4; j++) {
        int row = wn + j * 16 + l15;
        boff[j] = ABUF + row * 32 + ((g ^ ((row ^ (row >> 2)) & 3)) << 3);
    }

#define STAGE3(bufi, kt) do { \
    _Pragma("unroll") for (int r_ = 0; r_ < RA; r_++) \
        GLDS16(Ag + asrc[r_] + (kt) * 32, &Buf[bufi][r_ * (TPB * 8) + w * 512]); \
    _Pragma("unroll") for (int r_ = 0; r_ < RB; r_++) \
        GLDS16(Bg + bsrc[r_] + (kt) * 32, &Buf[bufi][ABUF + r_ * (TPB * 8) + w * 512]); \
} while (0)

    f32x4 acc[4][4] = {};
    const int NT = K >> 5;                 // 48 (divisible by 3)

    STAGE3(0, 0);
    STAGE3(1, 1);

#pragma unroll 1
    for (int t = 0; t < NT; t += 3) {
#pragma unroll
        for (int u = 0; u < 3; u++) {
            asm volatile("s_waitcnt vmcnt(%0)" :: "n"(LPS) : "memory");
            __builtin_amdgcn_s_barrier();
            __builtin_amdgcn_sched_barrier(0);
            if (t + u + 2 < NT) {
                constexpr int NB3[3] = {2, 0, 1};
                STAGE3(NB3[u], t + u + 2);
            }
            __builtin_amdgcn_sched_barrier(0);

            f16x8 af[4], bf[4];
#pragma unroll
            for (int i = 0; i < 4; i++) af[i] = *(const f16x8*)&Buf[u][aoff[i]];
#pragma unroll
            for (int j = 0; j < 4; j++) bf[j] = *(const f16x8*)&Buf[u][boff[j]];
            __builtin_amdgcn_s_setprio(1);
#pragma unroll
            for (int i = 0; i < 4; i++)
#pragma unroll
                for (int j = 0; j < 4; j++)
                    acc[i][j] = mfma16(af[i], bf[j], acc[i][j]);
            __builtin_amdgcn_s_setprio(0);
        }
    }
#undef STAGE3

    // ---- epilogue ----
#pragma unroll
    for (int i = 0; i < 4; i++) {
#pragma unroll
        for (int j = 0; j < 4; j++) {
            const int n = n0 + wn + j * 16 + l15;
            const int mb = m0 + wm + i * 16 + g * 4;
            if (MODE == 4 && sel) {            // V^T [B,H,96,TK]
                int bq = mb / T, t = mb - bq * T;
                int hh = n / HD, hd = n - hh * HD;
                f16x4 pk;
#pragma unroll
                for (int r = 0; r < 4; r++) pk[r] = (f16)(acc[i][j][r] + bias[n]);
                *(f16x4*)&((f16*)outp)[(((long)bq * NH + hh) * HD + hd) * TK + t] = pk;
            } else if (MODE == 4) {            // K padded [B,H,T,128]
#pragma unroll
                for (int r = 0; r < 4; r++) {
                    int m = mb + r;
                    int bq = m / T, t = m - bq * T;
                    int hh = n / HD, hd = n - hh * HD;
                    ((f16*)outp)[(((long)bq * NH + hh) * T + t) * 128 + hd] = (f16)(acc[i][j][r] + bias[n]);
                }
            } else if (MODE == 5) {            // Q [B,H,T,96]
#pragma unroll
                for (int r = 0; r < 4; r++) {
                    int m = mb + r;
                    int bq = m / T, t = m - bq * T;
                    int hh = n / HD, hd = n - hh * HD;
                    ((f16*)outp)[(((long)bq * NH + hh) * T + t) * 96 + hd] = (f16)(acc[i][j][r] + bias[n]);
                }
            } else {                           // f32 row-major
#pragma unroll
                for (int r = 0; r < 4; r++)
                    ((float*)outp)[(long)(mb + r) * N + n] = acc[i][j][r] + bias[n];
            }
        }
    }
}

// ---------------- Flash attention (round-3 structure, unchanged) ----------------
__global__ __launch_bounds__(256, 2) void attn_fwd(
    const f16* __restrict__ Q, const f16* __restrict__ Kg,
    const f16* __restrict__ Vg, f16* __restrict__ O) {
    __shared__ f16 Kl[2][64 * 128];
    __shared__ f16 Vl[2][96 * 64];
    __shared__ f16 Pl[4][32 * 64];

    const int tid = threadIdx.x, w = tid >> 6, lane = tid & 63;
    const int q31 = lane & 31, hf = lane >> 5;
    const int half = w >> 1, u = w & 1;

    const int linear = blockIdx.x + (int)(gridDim.x * (blockIdx.y + gridDim.y * blockIdx.z));
    const int wid = (linear & 7) * 64 + (linear >> 3);
    const int qc = wid & 15, h = (wid >> 4) & 15, b = wid >> 8;

    const long kbase = (long)(b * NH + h) * TK * 128;
    const long vbase = (long)(b * NH + h) * HD * TK;
    const long qbase = (long)(b * NH + h) * TQ * 96;
    const int q0 = qc * 64 + u * 32;

    int ksrc[8], vsrc[6];
#pragma unroll
    for (int i = 0; i < 8; i++) {
        int L = (u * 8 + i) * 1024 + lane * 16;
        int r = L >> 8, s = (L >> 4) & 15;
        ksrc[i] = r * 128 + ((s ^ (r & 7)) << 3);
    }
#pragma unroll
    for (int i = 0; i < 6; i++) {
        int L = (u * 6 + i) * 1024 + lane * 16;
        int r = L >> 7, s = (L >> 4) & 7;
        vsrc[i] = r * TK + ((s ^ (r & 7)) << 3);
    }

    f16x8 qf[6];
#pragma unroll
    for (int s = 0; s < 6; s++)
        qf[s] = *(const f16x8*)&Q[qbase + (long)(q0 + q31) * 96 + hf * 8 + 16 * s];

    float mx = -3e38f, ls = 0.f;
    f32x16 acc[3] = {};

#define STAGE(c_) do { \
    const f16* kp_ = Kg + kbase + (long)(half * 16 + (c_)) * (64 * 128); \
    _Pragma("unroll") for (int i_ = 0; i_ < 8; i_++) \
        GLDS16(kp_ + ksrc[i_], &Kl[half][(u * 8 + i_) * 512]); \
    const f16* vp_ = Vg + vbase + (half * 16 + (c_)) * 64; \
    _Pragma("unroll") for (int i_ = 0; i_ < 6; i_++) \
        GLDS16(vp_ + vsrc[i_], &Vl[half][(u * 6 + i_) * 512]); \
} while (0)

    STAGE(0);

    for (int c = 0; c < 16; ++c) {
        __syncthreads();

        f32x16 st[2] = {};
#pragma unroll
        for (int kt = 0; kt < 2; kt++)
#pragma unroll
            for (int s = 0; s < 6; s++) {
                f16x8 kf = *(const f16x8*)&Kl[half][(kt * 32 + q31) * 128 +
                                                    (((hf + 2 * s) ^ (q31 & 7)) << 3)];
                st[kt] = __builtin_amdgcn_mfma_f32_32x32x16_f16(kf, qf[s], st[kt], 0, 0, 0);
            }

        float t16[16];
#pragma unroll
        for (int r = 0; r < 16; r++) t16[r] = fmaxf(st[0][r], st[1][r]);
#pragma unroll
        for (int o = 8; o >= 1; o >>= 1)
#pragma unroll
            for (int r = 0; r < o; r++) t16[r] = fmaxf(t16[r], t16[r + o]);
        float cm = fmaxf(t16[0], __shfl_xor(t16[0], 32));
        float mn = fmaxf(mx, cm);
        float corr = exp2f(mx - mn);
        mx = mn;
#pragma unroll
        for (int kt = 0; kt < 2; kt++)
#pragma unroll
            for (int r = 0; r < 16; r++) st[kt][r] = exp2f(st[kt][r] - mn);
        float s16[16];
#pragma unroll
        for (int r = 0; r < 16; r++) s16[r] = st[0][r] + st[1][r];
#pragma unroll
        for (int o = 8; o >= 1; o >>= 1)
#pragma unroll
            for (int r = 0; r < o; r++) s16[r] += s16[r + o];
        ls = ls * corr + s16[0];
#pragma unroll
        for (int dt = 0; dt < 3; dt++)
#pragma unroll
            for (int r = 0; r < 16; r++) acc[dt][r] *= corr;

#pragma unroll
        for (int kt = 0; kt < 2; kt++)
#pragma unroll
            for (int jq = 0; jq < 4; jq++) {
                f16x4 pk;
#pragma unroll
                for (int e = 0; e < 4; e++) pk[e] = (f16)st[kt][jq * 4 + e];
                int seg = kt * 4 + jq;
                *(f16x4*)&Pl[w][q31 * 64 + ((seg ^ (q31 & 7)) << 3) + hf * 4] = pk;
            }

#pragma unroll
        for (int ks = 0; ks < 4; ks++) {
            f16x8 pf = *(const f16x8*)&Pl[w][q31 * 64 + (((hf + 2 * ks) ^ (q31 & 7)) << 3)];
#pragma unroll
            for (int dt = 0; dt < 3; dt++) {
                f16x8 vf = *(const f16x8*)&Vl[half][(dt * 32 + q31) * 64 +
                                                    (((hf + 2 * ks) ^ (q31 & 7)) << 3)];
                acc[dt] = __builtin_amdgcn_mfma_f32_32x32x16_f16(vf, pf, acc[dt], 0, 0, 0);
            }
        }

        __syncthreads();
        if (c < 15) STAGE(c + 1);
    }

    ls += __shfl_xor(ls, 32);
    float* dump = (float*)&Kl[0][0] + u * (64 * 52);
    __syncthreads();
    if (half == 1) {
        float* dl = dump + lane * 52;
        dl[0] = mx; dl[1] = ls;
#pragma unroll
        for (int dt = 0; dt < 3; dt++)
#pragma unroll
            for (int r = 0; r < 16; r++) dl[2 + dt * 16 + r] = acc[dt][r];
    }
    __syncthreads();
    if (half == 0) {
        const float* dl = dump + lane * 52;
        float mb = dl[0], lsb = dl[1];
        float mf = fmaxf(mx, mb);
        float ca = exp2f(mx - mf), cb = exp2f(mb - mf);
        float inv = 1.f / (ls * ca + lsb * cb);
        const long orow = (long)(b * TQ + q0 + q31) * DM + h * 96;
#pragma unroll
        for (int dt = 0; dt < 3; dt++)
#pragma unroll
            for (int jq = 0; jq < 4; jq++) {
                f16x4 ov;
#pragma unroll
                for (int e = 0; e < 4; e++) {
                    int r = jq * 4 + e;
                    ov[e] = (f16)((acc[dt][r] * ca + dl[2 + dt * 16 + r] * cb) * inv);
                }
                *(f16x4*)&O[orow + dt * 32 + jq * 8 + hf * 4] = ov;
            }
    }
}

// ---------------- host ----------------
extern "C" void kernel_launch(void* const* d_in, const int* in_sizes, int n_in,
                              void* d_out, int out_size, void* d_ws, size_t ws_size,
                              hipStream_t stream) {
    const float* x   = (const float*)d_in[0];
    const float* mem = (const float*)d_in[1];
    const float* qc  = (const float*)d_in[2];
    const float* mc  = (const float*)d_in[3];
    const float* Wq  = (const float*)d_in[4];
    const float* bq  = (const float*)d_in[5];
    const float* Wk  = (const float*)d_in[6];
    const float* bk  = (const float*)d_in[7];
    const float* Wv  = (const float*)d_in[8];
    const float* bv  = (const float*)d_in[9];
    const float* Wo  = (const float*)d_in[10];
    const float* bo  = (const float*)d_in[11];
    float* out = (float*)d_out;

    const long nx  = (long)NB * TQ * DM;
    const long nm  = (long)NB * TK * DM;
    const long nw  = (long)DM * DM;
    const long nq  = (long)NB * NH * TQ * 96;
    const long nkp = (long)NB * NH * TK * 128;
    const long nvt = (long)NB * NH * HD * TK;

    char* ws = (char*)d_ws;
    size_t off = 0;
    auto alloc = [&](size_t bytes) { size_t o = off; off = (off + bytes + 255) & ~(size_t)255; return o; };
    f16* x16   = (f16*)(ws + alloc(nx * 2));     // reused as at16 after Q-proj
    f16* mem16 = (f16*)(ws + alloc(nm * 2));
    f16* wq16  = (f16*)(ws + alloc(nw * 2));
    f16* wk16  = (f16*)(ws + alloc(nw * 2));
    f16* wv16  = (f16*)(ws + alloc(nw * 2));
    f16* wo16  = (f16*)(ws + alloc(nw * 2));
    f16* q16   = (f16*)(ws + alloc(nq * 2));
    f16* k16p  = (f16*)(ws + alloc(nkp * 2));
    f16* vt16  = (f16*)(ws + alloc(nvt * 2));
    float* sinq = (float*)(ws + alloc((size_t)NB * TQ * 48 * 4));
    float* cosq = (float*)(ws + alloc((size_t)NB * TQ * 48 * 4));
    float* sink = (float*)(ws + alloc((size_t)NB * TK * 48 * 4));
    float* cosk = (float*)(ws + alloc((size_t)NB * TK * 48 * 4));
    f16* at16 = x16;

    cvt_w4<<<dim3((int)(nw / 4 / 256), 4), 256, 0, stream>>>(
        (const float4*)Wq, (const float4*)Wk, (const float4*)Wv, (const float4*)Wo,
        (f16x4*)wq16, (f16x4*)wk16, (f16x4*)wv16, (f16x4*)wo16, (int)(nw / 4));
    cvt_xm<<<dim3((int)(nm / 4 / 256), 2), 256, 0, stream>>>(
        (const float4*)x, (const float4*)mem, (f16x4*)x16, (f16x4*)mem16,
        (int)(nx / 4), (int)(nm / 4));

    rope_tab2<<<dim3((NB * TK * 48 + 255) / 256, 2), 256, 0, stream>>>(
        qc, mc, sinq, cosq, sink, cosk, NB * TQ * 48, NB * TK * 48);

    // projections: Q (128x128, 256 thr, 192 blocks), fused K|V (256x128, 512 thr, 384 blocks)
    gemm3p<5, 128><<<dim3(12, 16), 256, 0, stream>>>(
        x16, wq16, nullptr, bq, nullptr, q16, nullptr, NB * TQ, DM, DM, TQ);
    gemm3p<4, 256><<<dim3(24, 16), 512, 0, stream>>>(
        mem16, wk16, wv16, bk, bv, k16p, vt16, NB * TK, DM, DM, TK);

    const float qscale = 0.10206207261596577f * 1.4426950408889634f;  // 1/sqrt(96)*log2(e)
    rope_apply_k<<<(NB * NH * TQ * 48 + 255) / 256, 256, 0, stream>>>(
        q16, sinq, cosq, TQ, 96, qscale, NB * NH * TQ * 48);
    rope_apply_k<<<(NB * NH * TK * 48 + 255) / 256, 256, 0, stream>>>(
        k16p, sink, cosk, TK, 128, 1.0f, NB * NH * TK * 48);

    attn_fwd<<<dim3(16, 16, 2), 256, 0, stream>>>(q16, k16p, vt16, at16);

    gemm3p<1, 128><<<dim3(12, 16), 256, 0, stream>>>(
        at16, wo16, nullptr, bo, nullptr, out, nullptr, NB * TQ, DM, DM, TQ);
}

// Round 7
// 158.721 us; speedup vs baseline: 1.2951x; 1.2933x over previous
//
#include <hip/hip_runtime.h>
#include <math.h>

typedef _Float16 f16;
typedef __attribute__((ext_vector_type(4))) _Float16 f16x4;
typedef __attribute__((ext_vector_type(8))) _Float16 f16x8;
typedef __attribute__((ext_vector_type(4))) float f32x4;
typedef __attribute__((ext_vector_type(16))) float f32x16;

#define NB 2
#define NH 16
#define TQ 1024
#define TK 2048
#define DM 1536
#define HD 96
#define RH 48

__device__ __forceinline__ f32x4 mfma16(f16x8 a, f16x8 b, f32x4 c) {
    return __builtin_amdgcn_mfma_f32_16x16x32_f16(a, b, c, 0, 0, 0);
}

#define GLDS16(gptr, lptr) __builtin_amdgcn_global_load_lds( \
    (const __attribute__((address_space(1))) unsigned int*)(gptr), \
    (__attribute__((address_space(3))) unsigned int*)(lptr), 16, 0, 0)

// ---------------- conversions (fused launches) ----------------
__global__ void cvt_w4(const float4* __restrict__ W0, const float4* __restrict__ W1,
                       const float4* __restrict__ W2, const float4* __restrict__ W3,
                       f16x4* __restrict__ o0, f16x4* __restrict__ o1,
                       f16x4* __restrict__ o2, f16x4* __restrict__ o3, int n4) {
    int i = blockIdx.x * 256 + threadIdx.x;
    if (i >= n4) return;
    const float4* in = blockIdx.y == 0 ? W0 : blockIdx.y == 1 ? W1 : blockIdx.y == 2 ? W2 : W3;
    f16x4* out      = blockIdx.y == 0 ? o0 : blockIdx.y == 1 ? o1 : blockIdx.y == 2 ? o2 : o3;
    float4 v = in[i];
    f16x4 o;
    o[0] = (f16)v.x; o[1] = (f16)v.y; o[2] = (f16)v.z; o[3] = (f16)v.w;
    out[i] = o;
}

__global__ void cvt_xm(const float4* __restrict__ X, const float4* __restrict__ M,
                       f16x4* __restrict__ ox, f16x4* __restrict__ om, int nx4, int nm4) {
    int i = blockIdx.x * 256 + threadIdx.x;
    int n = blockIdx.y == 0 ? nx4 : nm4;
    if (i >= n) return;
    const float4* in = blockIdx.y == 0 ? X : M;
    f16x4* out = blockIdx.y == 0 ? ox : om;
    float4 v = in[i];
    f16x4 o;
    o[0] = (f16)v.x; o[1] = (f16)v.y; o[2] = (f16)v.z; o[3] = (f16)v.w;
    out[i] = o;
}

// ---------------- RoPE sin/cos tables: [B*T][48] ----------------
__global__ void rope_tab2(const float* __restrict__ cq, const float* __restrict__ cm,
                          float* __restrict__ sq, float* __restrict__ cqo,
                          float* __restrict__ sk, float* __restrict__ cko,
                          int nq, int nk) {
    int i = blockIdx.x * 256 + threadIdx.x;
    int n = blockIdx.y == 0 ? nq : nk;
    if (i >= n) return;
    const float* coords = blockIdx.y == 0 ? cq : cm;
    float* sinT = blockIdx.y == 0 ? sq : sk;
    float* cosT = blockIdx.y == 0 ? cqo : cko;
    int bt = i / 48, idx = i - bt * 48;
    int axis = idx >> 4, f = idx & 15;
    float inv = powf(10000.f, -(float)f * (1.f / 16.f));
    float ang = coords[bt * 3 + axis] * inv;
    sinT[i] = sinf(ang);
    cosT[i] = cosf(ang);
}

// ---------------- RoPE rotation in-place on [B,H,T,stride] f16 ----------------
__global__ void rope_apply_k(f16* __restrict__ qk, const float* __restrict__ sinT,
                             const float* __restrict__ cosT, int T, int stride,
                             float scale, int n) {
    int i = blockIdx.x * 256 + threadIdx.x;
    if (i >= n) return;
    int p = i % 48;
    int rest = i / 48;              // (b*NH + h)*T + t
    int t = rest % T;
    int b = rest / (NH * T);
    long base = (long)rest * stride;
    float x1 = (float)qk[base + p];
    float x2 = (float)qk[base + p + RH];
    int ti = (b * T + t) * 48 + p;
    float s = sinT[ti], c = cosT[ti];
    qk[base + p]      = (f16)((x1 * c - x2 * s) * scale);
    qk[base + p + RH] = (f16)((x2 * c + x1 * s) * scale);
}

// ---------------- GEMM v4: 2-buf depth-1 pipeline, BK=64, counted vmcnt ----------------
// CFG 0: fused QKV. BM=BN=256, 512 thr (8 waves 2Mx4N, wave tile 128x64).
//   Grid 240 = 48 Q-blocks + 96 K + 96 V (one dispatch round).
//   Epilogues: Q -> [B,H,TQ,96] f16; K -> padded [B,H,TK,128]; V -> V^T [B,H,96,TK].
// CFG 1: O-proj. BM=BN=128, 256 thr (4 waves 2x2, wave tile 64x64), 2 blocks/CU,
//   grid 192, f32 row-major out.
// Loop: STAGE(t+1)->buf[(t+1)&1]; vmcnt(8) [stage(t) landed]; barrier; compute buf[t&1];
// barrier.  Stage(t+1) has a full tile of cover; vmcnt never drained to 0 in-loop.
// LDS rows 128B, seg^(row&7) swizzle (16B segs) via pre-swizzled global source
// (round-4 proven: 0 bank conflicts).
template <int CFG>
__global__ __launch_bounds__(CFG == 0 ? 512 : 256, CFG == 0 ? 1 : 2)
void gemmP(const f16* __restrict__ Aq, const f16* __restrict__ Akv,
           const f16* __restrict__ Wqp, const f16* __restrict__ Wkp, const f16* __restrict__ Wvp,
           const float* __restrict__ bqp, const float* __restrict__ bkp, const float* __restrict__ bvp,
           f16* __restrict__ outq, f16* __restrict__ outk, f16* __restrict__ outv,
           float* __restrict__ outo) {
    constexpr int BMx = CFG == 0 ? 256 : 128;
    constexpr int BNx = CFG == 0 ? 256 : 128;
    constexpr int TPB = CFG == 0 ? 512 : 256;
    constexpr int MI  = CFG == 0 ? 8 : 4;
    constexpr int NI  = 4;
    constexpr int ABUF = BMx * 64;            // f16 per A region
    constexpr int BUFSZ = (BMx + BNx) * 64;   // f16 per buffer
    constexpr int NT = DM / 64;               // 24 K-tiles

    __shared__ f16 Buf[2][BUFSZ];

    const int tid = threadIdx.x, w = tid >> 6, lane = tid & 63;
    const int l15 = lane & 15, g = lane >> 4;

    int sel = 0, mt, nt;
    const f16* A; const f16* W; const float* bias;
    if constexpr (CFG == 0) {
        const int bid = blockIdx.x;
        const int wid = (bid & 7) * 30 + (bid >> 3);   // bijective (240 = 8*30)
        if (wid < 48)       { sel = 0; mt = wid / 6;        nt = wid - mt * 6;        A = Aq;  W = Wqp; bias = bqp; }
        else if (wid < 144) { sel = 1; int r = wid - 48;  mt = r / 6; nt = r - mt * 6; A = Akv; W = Wkp; bias = bkp; }
        else                { sel = 2; int r = wid - 144; mt = r / 6; nt = r - mt * 6; A = Akv; W = Wvp; bias = bvp; }
    } else {
        const int bid = blockIdx.x;
        const int wid = (bid & 7) * 24 + (bid >> 3);   // bijective (192 = 8*24)
        mt = wid / 12; nt = wid - mt * 12;
        A = Aq; W = Wqp; bias = bqp;
    }
    const int m0 = mt * BMx, n0 = nt * BNx;
    const int wm = (w & 1) * (MI * 16);
    const int wn = (w >> 1) * 64;

    // pre-swizzled per-lane global source offsets (f16 units); 4 rounds each for A and B
    int src[4];
#pragma unroll
    for (int r = 0; r < 4; r++) {
        int L = r * (TPB * 16) + tid * 16;   // linear LDS byte offset within region
        int row = L >> 7, seg = (L >> 4) & 7;
        src[r] = row * DM + ((seg ^ (row & 7)) << 3);
    }
    const f16* Ag = A + (long)m0 * DM;
    const f16* Bg = W + (long)n0 * DM;

    // fragment LDS element offsets
    int aoff[MI][2], boff[NI][2];
#pragma unroll
    for (int i = 0; i < MI; i++) {
        int row = wm + i * 16 + l15;
#pragma unroll
        for (int s = 0; s < 2; s++)
            aoff[i][s] = row * 64 + (((s * 4 + g) ^ (row & 7)) << 3);
    }
#pragma unroll
    for (int j = 0; j < NI; j++) {
        int row = wn + j * 16 + l15;
#pragma unroll
        for (int s = 0; s < 2; s++)
            boff[j][s] = ABUF + row * 64 + (((s * 4 + g) ^ (row & 7)) << 3);
    }

#define STG(bufp, kt) do { \
    _Pragma("unroll") for (int r_ = 0; r_ < 4; r_++) { \
        GLDS16(Ag + src[r_] + (kt) * 64, &Buf[bufp][r_ * (TPB * 8) + w * 512]); \
        GLDS16(Bg + src[r_] + (kt) * 64, &Buf[bufp][ABUF + r_ * (TPB * 8) + w * 512]); \
    } \
} while (0)

    f32x4 acc[MI][NI] = {};

#define COMPUTE(bufp) do { \
    f16x8 bf[NI][2]; \
    _Pragma("unroll") for (int j_ = 0; j_ < NI; j_++) \
        _Pragma("unroll") for (int s_ = 0; s_ < 2; s_++) \
            bf[j_][s_] = *(const f16x8*)&Buf[bufp][boff[j_][s_]]; \
    __builtin_amdgcn_s_setprio(1); \
    _Pragma("unroll") for (int i_ = 0; i_ < MI; i_++) { \
        f16x8 a0 = *(const f16x8*)&Buf[bufp][aoff[i_][0]]; \
        f16x8 a1 = *(const f16x8*)&Buf[bufp][aoff[i_][1]]; \
        _Pragma("unroll") for (int j_ = 0; j_ < NI; j_++) { \
            acc[i_][j_] = mfma16(a0, bf[j_][0], acc[i_][j_]); \
            acc[i_][j_] = mfma16(a1, bf[j_][1], acc[i_][j_]); \
        } \
    } \
    __builtin_amdgcn_s_setprio(0); \
} while (0)

    STG(0, 0);
#pragma unroll 1
    for (int t = 0; t < NT; t += 2) {
        // even tile t: stage t+1 -> buf1, compute buf0
        STG(1, t + 1);
        asm volatile("s_waitcnt vmcnt(8)" ::: "memory");
        __builtin_amdgcn_s_barrier();
        __builtin_amdgcn_sched_barrier(0);
        COMPUTE(0);
        __builtin_amdgcn_sched_barrier(0);
        __builtin_amdgcn_s_barrier();
        // odd tile t+1: stage t+2 -> buf0, compute buf1
        if (t + 2 < NT) {
            STG(0, t + 2);
            asm volatile("s_waitcnt vmcnt(8)" ::: "memory");
        } else {
            asm volatile("s_waitcnt vmcnt(0)" ::: "memory");
        }
        __builtin_amdgcn_s_barrier();
        __builtin_amdgcn_sched_barrier(0);
        COMPUTE(1);
        __builtin_amdgcn_sched_barrier(0);
        __builtin_amdgcn_s_barrier();
    }
#undef STG
#undef COMPUTE

    // ---- epilogue ----
#pragma unroll
    for (int i = 0; i < MI; i++) {
#pragma unroll
        for (int j = 0; j < NI; j++) {
            const int n = n0 + wn + j * 16 + l15;
            const int mb = m0 + wm + i * 16 + g * 4;
            if constexpr (CFG == 1) {
#pragma unroll
                for (int r = 0; r < 4; r++)
                    outo[(long)(mb + r) * DM + n] = acc[i][j][r] + bias[n];
            } else {
                const int hh = n / HD, hd = n - hh * HD;
                if (sel == 0) {            // Q [B,H,TQ,96]
#pragma unroll
                    for (int r = 0; r < 4; r++) {
                        int m = mb + r, bq = m >> 10, t = m & (TQ - 1);
                        outq[(((long)bq * NH + hh) * TQ + t) * 96 + hd] = (f16)(acc[i][j][r] + bias[n]);
                    }
                } else if (sel == 1) {     // K padded [B,H,TK,128]
#pragma unroll
                    for (int r = 0; r < 4; r++) {
                        int m = mb + r, bq = m >> 11, t = m & (TK - 1);
                        outk[(((long)bq * NH + hh) * TK + t) * 128 + hd] = (f16)(acc[i][j][r] + bias[n]);
                    }
                } else {                   // V^T [B,H,96,TK], pack 4 consecutive t
                    int bq = mb >> 11, t = mb & (TK - 1);
                    f16x4 pk;
#pragma unroll
                    for (int r = 0; r < 4; r++) pk[r] = (f16)(acc[i][j][r] + bias[n]);
                    *(f16x4*)&outv[(((long)bq * NH + hh) * HD + hd) * TK + t] = pk;
                }
            }
        }
    }
}

// ---------------- Flash attention (round-3 structure, unchanged) ----------------
__global__ __launch_bounds__(256, 2) void attn_fwd(
    const f16* __restrict__ Q, const f16* __restrict__ Kg,
    const f16* __restrict__ Vg, f16* __restrict__ O) {
    __shared__ f16 Kl[2][64 * 128];
    __shared__ f16 Vl[2][96 * 64];
    __shared__ f16 Pl[4][32 * 64];

    const int tid = threadIdx.x, w = tid >> 6, lane = tid & 63;
    const int q31 = lane & 31, hf = lane >> 5;
    const int half = w >> 1, u = w & 1;

    const int linear = blockIdx.x + (int)(gridDim.x * (blockIdx.y + gridDim.y * blockIdx.z));
    const int wid = (linear & 7) * 64 + (linear >> 3);
    const int qc = wid & 15, h = (wid >> 4) & 15, b = wid >> 8;

    const long kbase = (long)(b * NH + h) * TK * 128;
    const long vbase = (long)(b * NH + h) * HD * TK;
    const long qbase = (long)(b * NH + h) * TQ * 96;
    const int q0 = qc * 64 + u * 32;

    int ksrc[8], vsrc[6];
#pragma unroll
    for (int i = 0; i < 8; i++) {
        int L = (u * 8 + i) * 1024 + lane * 16;
        int r = L >> 8, s = (L >> 4) & 15;
        ksrc[i] = r * 128 + ((s ^ (r & 7)) << 3);
    }
#pragma unroll
    for (int i = 0; i < 6; i++) {
        int L = (u * 6 + i) * 1024 + lane * 16;
        int r = L >> 7, s = (L >> 4) & 7;
        vsrc[i] = r * TK + ((s ^ (r & 7)) << 3);
    }

    f16x8 qf[6];
#pragma unroll
    for (int s = 0; s < 6; s++)
        qf[s] = *(const f16x8*)&Q[qbase + (long)(q0 + q31) * 96 + hf * 8 + 16 * s];

    float mx = -3e38f, ls = 0.f;
    f32x16 acc[3] = {};

#define STAGE(c_) do { \
    const f16* kp_ = Kg + kbase + (long)(half * 16 + (c_)) * (64 * 128); \
    _Pragma("unroll") for (int i_ = 0; i_ < 8; i_++) \
        GLDS16(kp_ + ksrc[i_], &Kl[half][(u * 8 + i_) * 512]); \
    const f16* vp_ = Vg + vbase + (half * 16 + (c_)) * 64; \
    _Pragma("unroll") for (int i_ = 0; i_ < 6; i_++) \
        GLDS16(vp_ + vsrc[i_], &Vl[half][(u * 6 + i_) * 512]); \
} while (0)

    STAGE(0);

    for (int c = 0; c < 16; ++c) {
        __syncthreads();

        f32x16 st[2] = {};
#pragma unroll
        for (int kt = 0; kt < 2; kt++)
#pragma unroll
            for (int s = 0; s < 6; s++) {
                f16x8 kf = *(const f16x8*)&Kl[half][(kt * 32 + q31) * 128 +
                                                    (((hf + 2 * s) ^ (q31 & 7)) << 3)];
                st[kt] = __builtin_amdgcn_mfma_f32_32x32x16_f16(kf, qf[s], st[kt], 0, 0, 0);
            }

        float t16[16];
#pragma unroll
        for (int r = 0; r < 16; r++) t16[r] = fmaxf(st[0][r], st[1][r]);
#pragma unroll
        for (int o = 8; o >= 1; o >>= 1)
#pragma unroll
            for (int r = 0; r < o; r++) t16[r] = fmaxf(t16[r], t16[r + o]);
        float cm = fmaxf(t16[0], __shfl_xor(t16[0], 32));
        float mn = fmaxf(mx, cm);
        float corr = exp2f(mx - mn);
        mx = mn;
#pragma unroll
        for (int kt = 0; kt < 2; kt++)
#pragma unroll
            for (int r = 0; r < 16; r++) st[kt][r] = exp2f(st[kt][r] - mn);
        float s16[16];
#pragma unroll
        for (int r = 0; r < 16; r++) s16[r] = st[0][r] + st[1][r];
#pragma unroll
        for (int o = 8; o >= 1; o >>= 1)
#pragma unroll
            for (int r = 0; r < o; r++) s16[r] += s16[r + o];
        ls = ls * corr + s16[0];
#pragma unroll
        for (int dt = 0; dt < 3; dt++)
#pragma unroll
            for (int r = 0; r < 16; r++) acc[dt][r] *= corr;

#pragma unroll
        for (int kt = 0; kt < 2; kt++)
#pragma unroll
            for (int jq = 0; jq < 4; jq++) {
                f16x4 pk;
#pragma unroll
                for (int e = 0; e < 4; e++) pk[e] = (f16)st[kt][jq * 4 + e];
                int seg = kt * 4 + jq;
                *(f16x4*)&Pl[w][q31 * 64 + ((seg ^ (q31 & 7)) << 3) + hf * 4] = pk;
            }

#pragma unroll
        for (int ks = 0; ks < 4; ks++) {
            f16x8 pf = *(const f16x8*)&Pl[w][q31 * 64 + (((hf + 2 * ks) ^ (q31 & 7)) << 3)];
#pragma unroll
            for (int dt = 0; dt < 3; dt++) {
                f16x8 vf = *(const f16x8*)&Vl[half][(dt * 32 + q31) * 64 +
                                                    (((hf + 2 * ks) ^ (q31 & 7)) << 3)];
                acc[dt] = __builtin_amdgcn_mfma_f32_32x32x16_f16(vf, pf, acc[dt], 0, 0, 0);
            }
        }

        __syncthreads();
        if (c < 15) STAGE(c + 1);
    }

    ls += __shfl_xor(ls, 32);
    float* dump = (float*)&Kl[0][0] + u * (64 * 52);
    __syncthreads();
    if (half == 1) {
        float* dl = dump + lane * 52;
        dl[0] = mx; dl[1] = ls;
#pragma unroll
        for (int dt = 0; dt < 3; dt++)
#pragma unroll
            for (int r = 0; r < 16; r++) dl[2 + dt * 16 + r] = acc[dt][r];
    }
    __syncthreads();
    if (half == 0) {
        const float* dl = dump + lane * 52;
        float mb = dl[0], lsb = dl[1];
        float mf = fmaxf(mx, mb);
        float ca = exp2f(mx - mf), cb = exp2f(mb - mf);
        float inv = 1.f / (ls * ca + lsb * cb);
        const long orow = (long)(b * TQ + q0 + q31) * DM + h * 96;
#pragma unroll
        for (int dt = 0; dt < 3; dt++)
#pragma unroll
            for (int jq = 0; jq < 4; jq++) {
                f16x4 ov;
#pragma unroll
                for (int e = 0; e < 4; e++) {
                    int r = jq * 4 + e;
                    ov[e] = (f16)((acc[dt][r] * ca + dl[2 + dt * 16 + r] * cb) * inv);
                }
                *(f16x4*)&O[orow + dt * 32 + jq * 8 + hf * 4] = ov;
            }
    }
}

// ---------------- host ----------------
extern "C" void kernel_launch(void* const* d_in, const int* in_sizes, int n_in,
                              void* d_out, int out_size, void* d_ws, size_t ws_size,
                              hipStream_t stream) {
    const float* x   = (const float*)d_in[0];
    const float* mem = (const float*)d_in[1];
    const float* qc  = (const float*)d_in[2];
    const float* mc  = (const float*)d_in[3];
    const float* Wq  = (const float*)d_in[4];
    const float* bq  = (const float*)d_in[5];
    const float* Wk  = (const float*)d_in[6];
    const float* bk  = (const float*)d_in[7];
    const float* Wv  = (const float*)d_in[8];
    const float* bv  = (const float*)d_in[9];
    const float* Wo  = (const float*)d_in[10];
    const float* bo  = (const float*)d_in[11];
    float* out = (float*)d_out;

    const long nx  = (long)NB * TQ * DM;
    const long nm  = (long)NB * TK * DM;
    const long nw  = (long)DM * DM;
    const long nq  = (long)NB * NH * TQ * 96;
    const long nkp = (long)NB * NH * TK * 128;
    const long nvt = (long)NB * NH * HD * TK;

    char* ws = (char*)d_ws;
    size_t off = 0;
    auto alloc = [&](size_t bytes) { size_t o = off; off = (off + bytes + 255) & ~(size_t)255; return o; };
    f16* x16   = (f16*)(ws + alloc(nx * 2));     // reused as at16 after Q-proj
    f16* mem16 = (f16*)(ws + alloc(nm * 2));
    f16* wq16  = (f16*)(ws + alloc(nw * 2));
    f16* wk16  = (f16*)(ws + alloc(nw * 2));
    f16* wv16  = (f16*)(ws + alloc(nw * 2));
    f16* wo16  = (f16*)(ws + alloc(nw * 2));
    f16* q16   = (f16*)(ws + alloc(nq * 2));
    f16* k16p  = (f16*)(ws + alloc(nkp * 2));
    f16* vt16  = (f16*)(ws + alloc(nvt * 2));
    float* sinq = (float*)(ws + alloc((size_t)NB * TQ * 48 * 4));
    float* cosq = (float*)(ws + alloc((size_t)NB * TQ * 48 * 4));
    float* sink = (float*)(ws + alloc((size_t)NB * TK * 48 * 4));
    float* cosk = (float*)(ws + alloc((size_t)NB * TK * 48 * 4));
    f16* at16 = x16;

    cvt_w4<<<dim3((int)(nw / 4 / 256), 4), 256, 0, stream>>>(
        (const float4*)Wq, (const float4*)Wk, (const float4*)Wv, (const float4*)Wo,
        (f16x4*)wq16, (f16x4*)wk16, (f16x4*)wv16, (f16x4*)wo16, (int)(nw / 4));
    cvt_xm<<<dim3((int)(nm / 4 / 256), 2), 256, 0, stream>>>(
        (const float4*)x, (const float4*)mem, (f16x4*)x16, (f16x4*)mem16,
        (int)(nx / 4), (int)(nm / 4));

    rope_tab2<<<dim3((NB * TK * 48 + 255) / 256, 2), 256, 0, stream>>>(
        qc, mc, sinq, cosq, sink, cosk, NB * TQ * 48, NB * TK * 48);

    // fused QKV projection: 240 blocks (48 Q + 96 K + 96 V), one dispatch round
    gemmP<0><<<240, 512, 0, stream>>>(
        x16, mem16, wq16, wk16, wv16, bq, bk, bv, q16, k16p, vt16, nullptr);

    const float qscale = 0.10206207261596577f * 1.4426950408889634f;  // 1/sqrt(96)*log2(e)
    rope_apply_k<<<(NB * NH * TQ * 48 + 255) / 256, 256, 0, stream>>>(
        q16, sinq, cosq, TQ, 96, qscale, NB * NH * TQ * 48);
    rope_apply_k<<<(NB * NH * TK * 48 + 255) / 256, 256, 0, stream>>>(
        k16p, sink, cosk, TK, 128, 1.0f, NB * NH * TK * 48);

    attn_fwd<<<dim3(16, 16, 2), 256, 0, stream>>>(q16, k16p, vt16, at16);

    // output projection -> f32 (128x128 tiles, 192 blocks, 2 blocks/CU)
    gemmP<1><<<192, 256, 0, stream>>>(
        at16, nullptr, wo16, nullptr, nullptr, bo, nullptr, nullptr,
        nullptr, nullptr, nullptr, out);
}